// Round 5
// baseline (301.423 us; speedup 1.0000x reference)
//
#include <hip/hip_runtime.h>
#include <hip/hip_bf16.h>
#include <hip/hip_cooperative_groups.h>
#include <stdint.h>

namespace cg = cooperative_groups;

#define M_BATCH 1024
#define N_OUT   4096
#define K_IN    4096

#define BM 128
#define BN 128
#define BK 64
#define KPER  (K_IN / 2)        // 2048 per intra-block k-half
#define KITER (KPER / BK)       // 32

typedef __attribute__((ext_vector_type(8))) __bf16 bf16x8_t;
typedef __attribute__((ext_vector_type(4))) float f32x4_t;
typedef __attribute__((ext_vector_type(4))) float fvec4;   // clang vector: OK for nontemporal builtins

__device__ __forceinline__ unsigned short f2bf_bits(float f) {
    union { __hip_bfloat16 h; unsigned short u; } cvt;
    cvt.h = __float2bfloat16(f);  // RNE
    return cvt.u;
}

struct __align__(16) US8 { unsigned short s[8]; };

// Fused cooperative kernel. Grid = 256 blocks x 512 threads = 1 block/CU,
// co-resident (cooperative launch).
//
// Phase 1 (prep): block b (bn=b&31, bm=b>>5) converts
//   - weight B-panel slice: rows [bn*128 + bm*16, +16) of (mu + eps*sigma) -> bf16
//     (the 8 blocks sharing bn are on the same XCD under linear round-robin,
//      so the bn panel's bf16 image lands in the L2 the gemm will read it from)
//   - x slice: 1/32 of rows [bm*128, +128) -> bf16
// fp32 inputs are read nontemporal (dead after this; keep L2 for wb).
//
// Grid sync.
//
// Phase 2 (gemm): identical math to R4 — C = A@B^T + bias, 128x128 tile,
// 8 waves = 2 k-halves x 4 quadrant waves (64x64, acc[4][4]), LDS 2x64KB
// double buffer, XOR chunk swizzle on the global source address,
// global_load_lds width=16, single barrier per K-iter, LDS reduction of the
// two k-half partials in the epilogue, single fp32 store + fused bias.
__global__ __launch_bounds__(512, 2) void fused_kernel(
    const float* __restrict__ x,
    const float* __restrict__ wmu,
    const float* __restrict__ wsig,
    const float* __restrict__ bmu,
    const float* __restrict__ bsig,
    const float* __restrict__ epsw,
    const float* __restrict__ epsb,
    unsigned short* __restrict__ wb,
    unsigned short* __restrict__ xb,
    float* __restrict__ C)
{
    __shared__ unsigned short lds[2 * 32768];

    const int t  = threadIdx.x;
    const int bx = blockIdx.x;
    const int bn = bx & 31;
    const int bm = bx >> 5;

    // ---------------- Phase 1: prep ----------------
    {
        // Weights: this block's 16 rows of panel bn = 65536 f32 = 8192 units of 8.
        const size_t base4 = (size_t)bn * 131072 + (size_t)bm * 16384;  // fvec4 index
        const size_t base8 = (size_t)bn * 65536  + (size_t)bm * 8192;   // US8 index
        const fvec4* mu4 = (const fvec4*)wmu;
        const fvec4* sg4 = (const fvec4*)wsig;
        const fvec4* ep4 = (const fvec4*)epsw;
        US8* wb8 = (US8*)wb;
        #pragma unroll
        for (int c = 0; c < 16; ++c) {
            const int u = c * 512 + t;
            const size_t i4 = base4 + (size_t)u * 2;
            fvec4 m0 = __builtin_nontemporal_load(mu4 + i4);
            fvec4 m1 = __builtin_nontemporal_load(mu4 + i4 + 1);
            fvec4 s0 = __builtin_nontemporal_load(sg4 + i4);
            fvec4 s1 = __builtin_nontemporal_load(sg4 + i4 + 1);
            fvec4 e0 = __builtin_nontemporal_load(ep4 + i4);
            fvec4 e1 = __builtin_nontemporal_load(ep4 + i4 + 1);
            US8 o;
            o.s[0] = f2bf_bits(fmaf(e0.x, s0.x, m0.x));
            o.s[1] = f2bf_bits(fmaf(e0.y, s0.y, m0.y));
            o.s[2] = f2bf_bits(fmaf(e0.z, s0.z, m0.z));
            o.s[3] = f2bf_bits(fmaf(e0.w, s0.w, m0.w));
            o.s[4] = f2bf_bits(fmaf(e1.x, s1.x, m1.x));
            o.s[5] = f2bf_bits(fmaf(e1.y, s1.y, m1.y));
            o.s[6] = f2bf_bits(fmaf(e1.z, s1.z, m1.z));
            o.s[7] = f2bf_bits(fmaf(e1.w, s1.w, m1.w));
            wb8[base8 + u] = o;
        }

        // x: rows [bm*128,+128) = 65536 units of 8, split 32 ways by bn.
        const size_t xbase8 = (size_t)bm * 65536 + (size_t)bn * 2048;
        const fvec4* x4 = (const fvec4*)x;
        US8* xb8 = (US8*)xb;
        #pragma unroll
        for (int c = 0; c < 4; ++c) {
            const int u = c * 512 + t;
            const size_t i4 = (xbase8 + u) * 2;
            fvec4 v0 = __builtin_nontemporal_load(x4 + i4);
            fvec4 v1 = __builtin_nontemporal_load(x4 + i4 + 1);
            US8 o;
            o.s[0] = f2bf_bits(v0.x);
            o.s[1] = f2bf_bits(v0.y);
            o.s[2] = f2bf_bits(v0.z);
            o.s[3] = f2bf_bits(v0.w);
            o.s[4] = f2bf_bits(v1.x);
            o.s[5] = f2bf_bits(v1.y);
            o.s[6] = f2bf_bits(v1.z);
            o.s[7] = f2bf_bits(v1.w);
            xb8[xbase8 + u] = o;
        }
    }

    cg::this_grid().sync();

    // ---------------- Phase 2: gemm ----------------
    const unsigned short* A = xb;
    const unsigned short* B = wb;
    const int bm0   = bm * BM;
    const int bn0   = bn * BN;
    const int lane  = t & 63;
    const int wave  = t >> 6;
    const int khalf = wave >> 2;
    const int quadw = wave & 3;
    const int wrow  = (quadw >> 1) * 64;
    const int wcol  = (quadw & 1) * 64;
    const int lm    = lane & 15;
    const int quad  = lane >> 4;

    f32x4_t acc[4][4] = {};

    const unsigned short* srcs[8];
    const int rlow = t >> 3;                      // 0..63
    const int jsw  = ((t & 7) ^ (rlow & 7)) * 8;  // swizzled source k-offset (elems)
    #pragma unroll
    for (int s = 0; s < 8; ++s) {
        const int row  = rlow + (s & 1) * 64;
        const int half = (s >> 1) & 1;
        const unsigned short* base = (s < 4)
            ? (A + (size_t)(bm0 + row) * K_IN)
            : (B + (size_t)(bn0 + row) * K_IN);
        srcs[s] = base + half * KPER + jsw;
    }
    char* dst0 = (char*)lds + t * 16;

    #pragma unroll
    for (int s = 0; s < 8; ++s)
        __builtin_amdgcn_global_load_lds(
            (const __attribute__((address_space(1))) void*)(srcs[s]),
            (__attribute__((address_space(3))) void*)(dst0 + s * 8192), 16, 0, 0);

    for (int it = 0; it < KITER; ++it) {
        __syncthreads();

        if (it + 1 < KITER) {
            const int koff = (it + 1) * BK;
            const int nb   = ((it + 1) & 1) * 65536;
            #pragma unroll
            for (int s = 0; s < 8; ++s)
                __builtin_amdgcn_global_load_lds(
                    (const __attribute__((address_space(1))) void*)(srcs[s] + koff),
                    (__attribute__((address_space(3))) void*)(dst0 + nb + s * 8192), 16, 0, 0);
        }

        const unsigned short* Lb = lds + (it & 1) * 32768;
        const unsigned short* Ah = Lb + khalf * 8192;
        const unsigned short* Bh = Lb + 16384 + khalf * 8192;

        #pragma unroll
        for (int kk = 0; kk < 2; ++kk) {
            const int p = ((kk * 4) + quad) ^ (lm & 7);
            bf16x8_t a_frag[4], b_frag[4];
            #pragma unroll
            for (int im = 0; im < 4; im++)
                a_frag[im] = *(const bf16x8_t*)(Ah + ((wrow + im * 16 + lm) * 8 + p) * 8);
            #pragma unroll
            for (int jn = 0; jn < 4; jn++)
                b_frag[jn] = *(const bf16x8_t*)(Bh + ((wcol + jn * 16 + lm) * 8 + p) * 8);
            #pragma unroll
            for (int im = 0; im < 4; im++)
                #pragma unroll
                for (int jn = 0; jn < 4; jn++)
                    acc[im][jn] = __builtin_amdgcn_mfma_f32_16x16x32_bf16(
                        a_frag[im], b_frag[jn], acc[im][jn], 0, 0, 0);
        }
    }

    // Epilogue: reduce k-halves via LDS (reuses buffer 0; last compute used
    // buffer 1 — disjoint), add bias, store once.
    f32x4_t* red = (f32x4_t*)lds;
    if (wave >= 4) {
        #pragma unroll
        for (int im = 0; im < 4; im++)
            #pragma unroll
            for (int jn = 0; jn < 4; jn++)
                red[quadw * 1024 + (im * 4 + jn) * 64 + lane] = acc[im][jn];
    }
    __syncthreads();
    if (wave < 4) {
        #pragma unroll
        for (int jn = 0; jn < 4; jn++) {
            const int gn = bn0 + wcol + jn * 16 + lm;
            const float bias = bmu[gn] + epsb[gn] * bsig[gn];
            #pragma unroll
            for (int im = 0; im < 4; im++) {
                const f32x4_t part = red[quadw * 1024 + (im * 4 + jn) * 64 + lane];
                const int gm0 = bm0 + wrow + im * 16 + quad * 4;
                #pragma unroll
                for (int r = 0; r < 4; r++)
                    C[(size_t)(gm0 + r) * N_OUT + gn] = acc[im][jn][r] + part[r] + bias;
            }
        }
    }
}

// Insurance path if d_ws is too small for the bf16 staging buffers.
__global__ __launch_bounds__(256) void naive_kernel(
    const float* __restrict__ x, const float* __restrict__ wmu,
    const float* __restrict__ wsig, const float* __restrict__ bmu,
    const float* __restrict__ bsig, const float* __restrict__ epsw,
    const float* __restrict__ epsb, float* __restrict__ out)
{
    const int o = blockIdx.x * blockDim.x + threadIdx.x;
    const int b = blockIdx.y;
    const float4* xr = (const float4*)(x + (size_t)b * K_IN);
    const float4* mr = (const float4*)(wmu + (size_t)o * K_IN);
    const float4* sr = (const float4*)(wsig + (size_t)o * K_IN);
    const float4* er = (const float4*)(epsw + (size_t)o * K_IN);
    float s = 0.f;
    for (int k = 0; k < K_IN / 4; k++) {
        float4 xv = xr[k], m = mr[k], sg = sr[k], e = er[k];
        s += xv.x * fmaf(e.x, sg.x, m.x);
        s += xv.y * fmaf(e.y, sg.y, m.y);
        s += xv.z * fmaf(e.z, sg.z, m.z);
        s += xv.w * fmaf(e.w, sg.w, m.w);
    }
    out[(size_t)b * N_OUT + o] = s + bmu[o] + epsb[o] * bsig[o];
}

extern "C" void kernel_launch(void* const* d_in, const int* in_sizes, int n_in,
                              void* d_out, int out_size, void* d_ws, size_t ws_size,
                              hipStream_t stream)
{
    const float* x    = (const float*)d_in[0];
    const float* wmu  = (const float*)d_in[1];
    const float* wsig = (const float*)d_in[2];
    const float* bmu  = (const float*)d_in[3];
    const float* bsig = (const float*)d_in[4];
    const float* epsw = (const float*)d_in[5];
    const float* epsb = (const float*)d_in[6];
    float* out = (float*)d_out;

    const size_t need = ((size_t)N_OUT * K_IN + (size_t)M_BATCH * K_IN) * sizeof(unsigned short);
    if (ws_size >= need) {
        unsigned short* wb = (unsigned short*)d_ws;                  // [N][K] bf16
        unsigned short* xb = wb + (size_t)N_OUT * K_IN;              // [M][K] bf16
        void* args[] = { (void*)&x, (void*)&wmu, (void*)&wsig, (void*)&bmu,
                         (void*)&bsig, (void*)&epsw, (void*)&epsb,
                         (void*)&wb, (void*)&xb, (void*)&out };
        hipLaunchCooperativeKernel((const void*)fused_kernel,
                                   dim3(256), dim3(512), args, 0, stream);
    } else {
        dim3 grid(N_OUT / 256, M_BATCH);
        naive_kernel<<<grid, 256, 0, stream>>>(x, wmu, wsig, bmu, bsig, epsw, epsb, out);
    }
}

// Round 6
// 242.087 us; speedup vs baseline: 1.2451x; 1.2451x over previous
//
#include <hip/hip_runtime.h>
#include <hip/hip_bf16.h>
#include <stdint.h>

#define M_BATCH 1024
#define N_OUT   4096
#define K_IN    4096

#define BM 128
#define BN 128
#define BK 64
#define KPER  (K_IN / 2)        // 2048 per intra-block k-half
#define KITER (KPER / BK)       // 32

typedef __attribute__((ext_vector_type(8))) __bf16 bf16x8_t;
typedef __attribute__((ext_vector_type(4))) float f32x4_t;
typedef __attribute__((ext_vector_type(4))) float fvec4;   // clang vector: OK for nontemporal builtins

__device__ __forceinline__ unsigned short f2bf_bits(float f) {
    union { __hip_bfloat16 h; unsigned short u; } cvt;
    cvt.h = __float2bfloat16(f);  // RNE
    return cvt.u;
}

struct __align__(8) US4 { unsigned short x, y, z, w; };

// Kernel 1: w_bf16 = bf16(mu + eps*sigma); x_bf16 = bf16(x).
// 1M threads, exact trip counts, all loads hoisted for ILP (13 in flight).
// Nontemporal loads on the fp32 streams (dead after this kernel).
__global__ __launch_bounds__(256) void prep_kernel(
    const float* __restrict__ x,
    const float* __restrict__ wmu,
    const float* __restrict__ wsig,
    const float* __restrict__ epsw,
    unsigned short* __restrict__ wb,
    unsigned short* __restrict__ xb)
{
    const size_t tid = (size_t)blockIdx.x * blockDim.x + threadIdx.x;
    const size_t T   = (size_t)1048576;          // 4096 blocks x 256 threads

    const fvec4* wmu4  = (const fvec4*)wmu;
    const fvec4* wsig4 = (const fvec4*)wsig;
    const fvec4* epsw4 = (const fvec4*)epsw;
    US4* wb4 = (US4*)wb;

    fvec4 m[4], s[4], e[4];
    #pragma unroll
    for (int r = 0; r < 4; ++r) {
        const size_t i = tid + (size_t)r * T;    // NW4 = 4T exactly
        m[r] = __builtin_nontemporal_load(wmu4  + i);
        s[r] = __builtin_nontemporal_load(wsig4 + i);
        e[r] = __builtin_nontemporal_load(epsw4 + i);
    }
    #pragma unroll
    for (int r = 0; r < 4; ++r) {
        US4 o;
        o.x = f2bf_bits(fmaf(e[r].x, s[r].x, m[r].x));
        o.y = f2bf_bits(fmaf(e[r].y, s[r].y, m[r].y));
        o.z = f2bf_bits(fmaf(e[r].z, s[r].z, m[r].z));
        o.w = f2bf_bits(fmaf(e[r].w, s[r].w, m[r].w));
        wb4[tid + (size_t)r * T] = o;
    }

    // x: NX4 = T exactly, one fvec4 per thread.
    fvec4 v = __builtin_nontemporal_load((const fvec4*)x + tid);
    US4 o;
    o.x = f2bf_bits(v.x);
    o.y = f2bf_bits(v.y);
    o.z = f2bf_bits(v.z);
    o.w = f2bf_bits(v.w);
    ((US4*)xb)[tid] = o;
}

// Kernel 2: C = A @ B^T + bias, written once (no atomics, no pre-zero).
// A=[M][K] bf16, B=[N][K] bf16. 128x128 tile, grid 256 linear = 1 block/CU.
// XCD-aware decode: bn = (b&7) + 8*((b>>3)&3), bm = b>>5. Under round-robin
// block->XCD dispatch (XCD = b%8), the 8 blocks sharing a B-panel land on ONE
// XCD, whose 4 MB L2 holds exactly its 4 bf16 B-panels -> B-panel re-reads
// become L2 hits instead of LLC traffic (R5 evidence: ~460 MB of gemm fill
// came from LLC at ~12 TB/s = the gemm bottleneck). Performance-only heuristic.
// 512 threads = 8 waves: waves 0-3 compute k in [0,2048), waves 4-7
// k in [2048,4096), same four 64x64 quadrants (acc[4][4]); partials reduced
// through LDS in the epilogue. LDS: 2 x 64 KB double buffer; XOR chunk
// swizzle on the GLOBAL source address (de-swizzled at ds_read) keeps both
// fill and frag reads conflict-free. Single barrier per K-iter with
// prefetch-after-barrier so the global->LDS DMA overlaps MFMA.
__global__ __launch_bounds__(512, 2) void gemm_bt_kernel(
    const unsigned short* __restrict__ A,
    const unsigned short* __restrict__ B,
    const float* __restrict__ bmu,
    const float* __restrict__ bsig,
    const float* __restrict__ ebias,
    float* __restrict__ C)
{
    // Layout (per buffer, 4096 x 16B chunks = 64 KB):
    //   chunks [0,2048): A  = [half][128 rows][8 chunks]
    //   chunks [2048,4096): B, same shape.
    __shared__ unsigned short lds[2 * 32768];

    const int t   = threadIdx.x;
    const int b   = blockIdx.x;
    const int bn  = (b & 7) | (((b >> 3) & 3) << 3);   // 0..31, same-bn => same XCD
    const int bm  = b >> 5;                             // 0..7
    const int bm0 = bm * BM;
    const int bn0 = bn * BN;
    const int lane  = t & 63;
    const int wave  = t >> 6;
    const int khalf = wave >> 2;          // 0 or 1: which k-half this wave computes
    const int quadw = wave & 3;
    const int wrow  = (quadw >> 1) * 64;
    const int wcol  = (quadw & 1) * 64;
    const int lm    = lane & 15;
    const int quad  = lane >> 4;

    f32x4_t acc[4][4] = {};

    // Staging: thread t, step s stages global chunk g = t + 512*s into
    // LDS byte offset g*16. Decode: s<4 -> A, s>=4 -> B; half=(s>>1)&1;
    // row=(t>>3)+(s&1)*64; phys chunk j=t&7 -> fetch logical j^(row&7).
    const unsigned short* srcs[8];
    const int rlow = t >> 3;                      // 0..63
    const int jsw  = ((t & 7) ^ (rlow & 7)) * 8;  // swizzled source k-offset (elems)
    #pragma unroll
    for (int s = 0; s < 8; ++s) {
        const int row  = rlow + (s & 1) * 64;
        const int half = (s >> 1) & 1;
        const unsigned short* base = (s < 4)
            ? (A + (size_t)(bm0 + row) * K_IN)
            : (B + (size_t)(bn0 + row) * K_IN);
        srcs[s] = base + half * KPER + jsw;
    }
    char* dst0 = (char*)lds + t * 16;

    // Stage tile 0 into buffer 0.
    #pragma unroll
    for (int s = 0; s < 8; ++s)
        __builtin_amdgcn_global_load_lds(
            (const __attribute__((address_space(1))) void*)(srcs[s]),
            (__attribute__((address_space(3))) void*)(dst0 + s * 8192), 16, 0, 0);

    for (int it = 0; it < KITER; ++it) {
        __syncthreads();  // buf(it&1) ready; prior reads of other buf done

        if (it + 1 < KITER) {
            const int koff = (it + 1) * BK;
            const int nb   = ((it + 1) & 1) * 65536;
            #pragma unroll
            for (int s = 0; s < 8; ++s)
                __builtin_amdgcn_global_load_lds(
                    (const __attribute__((address_space(1))) void*)(srcs[s] + koff),
                    (__attribute__((address_space(3))) void*)(dst0 + nb + s * 8192), 16, 0, 0);
        }

        const unsigned short* Lb = lds + (it & 1) * 32768;
        const unsigned short* Ah = Lb + khalf * 8192;           // A, this wave's half
        const unsigned short* Bh = Lb + 16384 + khalf * 8192;   // B, this wave's half

        #pragma unroll
        for (int kk = 0; kk < 2; ++kk) {          // two 16x16x32 K-steps per BK=64
            const int p = ((kk * 4) + quad) ^ (lm & 7);  // de-swizzled chunk
            bf16x8_t a_frag[4], b_frag[4];
            #pragma unroll
            for (int im = 0; im < 4; im++)
                a_frag[im] = *(const bf16x8_t*)(Ah + ((wrow + im * 16 + lm) * 8 + p) * 8);
            #pragma unroll
            for (int jn = 0; jn < 4; jn++)
                b_frag[jn] = *(const bf16x8_t*)(Bh + ((wcol + jn * 16 + lm) * 8 + p) * 8);
            #pragma unroll
            for (int im = 0; im < 4; im++)
                #pragma unroll
                for (int jn = 0; jn < 4; jn++)
                    acc[im][jn] = __builtin_amdgcn_mfma_f32_16x16x32_bf16(
                        a_frag[im], b_frag[jn], acc[im][jn], 0, 0, 0);
        }
    }

    // Epilogue: reduce the two k-halves through LDS, add bias, store once.
    // Last compute used buffer 1 (bytes [64K,128K)); the 64 KB reduction
    // region reuses buffer 0 — disjoint, so no barrier needed before writes.
    f32x4_t* red = (f32x4_t*)lds;   // 4 regions x 1024 f32x4 (16 KB each)
    if (wave >= 4) {
        #pragma unroll
        for (int im = 0; im < 4; im++)
            #pragma unroll
            for (int jn = 0; jn < 4; jn++)
                red[quadw * 1024 + (im * 4 + jn) * 64 + lane] = acc[im][jn];
    }
    __syncthreads();
    if (wave < 4) {
        #pragma unroll
        for (int jn = 0; jn < 4; jn++) {
            const int gn = bn0 + wcol + jn * 16 + lm;
            const float bias = bmu[gn] + ebias[gn] * bsig[gn];
            #pragma unroll
            for (int im = 0; im < 4; im++) {
                const f32x4_t part = red[quadw * 1024 + (im * 4 + jn) * 64 + lane];
                const int gm0 = bm0 + wrow + im * 16 + quad * 4;
                #pragma unroll
                for (int r = 0; r < 4; r++)
                    C[(size_t)(gm0 + r) * N_OUT + gn] = acc[im][jn][r] + part[r] + bias;
            }
        }
    }
}

// Insurance path if d_ws is too small for the bf16 staging buffers.
__global__ __launch_bounds__(256) void naive_kernel(
    const float* __restrict__ x, const float* __restrict__ wmu,
    const float* __restrict__ wsig, const float* __restrict__ bmu,
    const float* __restrict__ bsig, const float* __restrict__ epsw,
    const float* __restrict__ epsb, float* __restrict__ out)
{
    const int o = blockIdx.x * blockDim.x + threadIdx.x;
    const int b = blockIdx.y;
    const float4* xr = (const float4*)(x + (size_t)b * K_IN);
    const float4* mr = (const float4*)(wmu + (size_t)o * K_IN);
    const float4* sr = (const float4*)(wsig + (size_t)o * K_IN);
    const float4* er = (const float4*)(epsw + (size_t)o * K_IN);
    float s = 0.f;
    for (int k = 0; k < K_IN / 4; k++) {
        float4 xv = xr[k], m = mr[k], sg = sr[k], e = er[k];
        s += xv.x * fmaf(e.x, sg.x, m.x);
        s += xv.y * fmaf(e.y, sg.y, m.y);
        s += xv.z * fmaf(e.z, sg.z, m.z);
        s += xv.w * fmaf(e.w, sg.w, m.w);
    }
    out[(size_t)b * N_OUT + o] = s + bmu[o] + epsb[o] * bsig[o];
}

extern "C" void kernel_launch(void* const* d_in, const int* in_sizes, int n_in,
                              void* d_out, int out_size, void* d_ws, size_t ws_size,
                              hipStream_t stream)
{
    const float* x    = (const float*)d_in[0];
    const float* wmu  = (const float*)d_in[1];
    const float* wsig = (const float*)d_in[2];
    const float* bmu  = (const float*)d_in[3];
    const float* bsig = (const float*)d_in[4];
    const float* epsw = (const float*)d_in[5];
    const float* epsb = (const float*)d_in[6];
    float* out = (float*)d_out;

    const size_t need = ((size_t)N_OUT * K_IN + (size_t)M_BATCH * K_IN) * sizeof(unsigned short);
    if (ws_size >= need) {
        unsigned short* wb = (unsigned short*)d_ws;                  // [N][K] bf16
        unsigned short* xb = wb + (size_t)N_OUT * K_IN;              // [M][K] bf16
        prep_kernel<<<4096, 256, 0, stream>>>(x, wmu, wsig, epsw, wb, xb);
        gemm_bt_kernel<<<256, 512, 0, stream>>>(xb, wb, bmu, bsig, epsb, out);
    } else {
        dim3 grid(N_OUT / 256, M_BATCH);
        naive_kernel<<<grid, 256, 0, stream>>>(x, wmu, wsig, bmu, bsig, epsw, epsb, out);
    }
}